// Round 10
// baseline (275.430 us; speedup 1.0000x reference)
//
#include <hip/hip_runtime.h>

#define N_NODES   50000
#define HID       64
#define N_GRAPHS  128
#define N_CLASSES 10
#define NP        196           // partitions of 256 nodes (196*256 = 50176)
#define EPA       8192          // edges per bucket block
#define PCAP      8192          // per-partition capacity in packed[] (>20 sigma)

typedef __attribute__((ext_vector_type(8))) short short8;
typedef __attribute__((ext_vector_type(4))) float f32x4;

__device__ __forceinline__ unsigned bf16rne(float f) {
    unsigned u = __float_as_uint(f);
    return (u + 0x7fffu + ((u >> 16) & 1u)) >> 16;
}
__device__ __forceinline__ unsigned pack_bf16x2(float lo, float hi) {
    return bf16rne(lo) | (bf16rne(hi) << 16);
}

// ---------------- x -> bf16 conversion + gcursor zero (launched FIRST) ----

__global__ void cvt_kernel(const float* __restrict__ x, unsigned short* __restrict__ xb,
                           int* __restrict__ gcursor) {
    if (blockIdx.x == 0 && threadIdx.x < NP) gcursor[threadIdx.x] = 0;
    int i = blockIdx.x * blockDim.x + threadIdx.x;
    if (i < N_NODES * 16) {
        float4 v = ((const float4*)x)[i];
        uint2 o;
        o.x = pack_bf16x2(v.x, v.y);
        o.y = pack_bf16x2(v.z, v.w);
        ((uint2*)xb)[i] = o;
    }
}

// ---------------- CSR build: 2-level LDS-staged counting sort -------------

__global__ __launch_bounds__(256) void bucket_kernel(
    const int* __restrict__ src, const int* __restrict__ dst,
    int* __restrict__ gcursor, unsigned* __restrict__ packed, int E) {
    __shared__ int hist[NP], scp[NP], base[NP], cnt2[NP];
    __shared__ int sc[256];
    __shared__ unsigned stag[EPA];
    const int t = threadIdx.x;
    const int e0 = blockIdx.x * EPA;
    const int e1 = min(e0 + EPA, E);
    for (int i = t; i < NP; i += 256) { hist[i] = 0; cnt2[i] = 0; }
    __syncthreads();
    for (int e = e0 + t; e < e1; e += 256)
        atomicAdd(&hist[dst[e] >> 8], 1);
    __syncthreads();
    sc[t] = (t < NP) ? hist[t] : 0;
    __syncthreads();
    for (int off = 1; off < 256; off <<= 1) {
        int add = (t >= off) ? sc[t - off] : 0;
        __syncthreads();
        sc[t] += add;
        __syncthreads();
    }
    if (t < NP) {
        scp[t] = sc[t] - hist[t];
        if (hist[t] > 0) base[t] = atomicAdd(&gcursor[t], hist[t]);
    }
    __syncthreads();
    for (int e = e0 + t; e < e1; e += 256) {
        int d = dst[e], s = src[e];
        int p = d >> 8;
        int idx = scp[p] + atomicAdd(&cnt2[p], 1);
        stag[idx] = (unsigned)s | ((unsigned)(d & 255) << 16) | ((unsigned)p << 24);
    }
    __syncthreads();
    const int n = e1 - e0;
    for (int i = t; i < n; i += 256) {
        unsigned v = stag[i];
        int p = v >> 24;
        packed[(size_t)p * PCAP + base[p] + (i - scp[p])] = v & 0x00FFFFFFu;
    }
}

// One block per partition. Integrated pscan, node offsets, LDS csr scatter,
// coalesced copy out.
__global__ __launch_bounds__(256) void build_kernel(
    const unsigned* __restrict__ packed, const int* __restrict__ gcursor,
    int* __restrict__ offsets, unsigned short* __restrict__ csr) {
    __shared__ int hist[256], lofs[256], cnt[256], sc[256], gv[256];
    __shared__ unsigned short lcsr[PCAP];
    const int p = blockIdx.x, t = threadIdx.x;

    int v = (t < NP) ? gcursor[t] : 0;
    sc[t] = v; gv[t] = v;
    __syncthreads();
    for (int off = 1; off < 256; off <<= 1) {
        int add = (t >= off) ? sc[t - off] : 0;
        __syncthreads();
        sc[t] += add;
        __syncthreads();
    }
    const int pb = sc[p] - gv[p];          // exclusive prefix at p
    const int ne = gv[p];
    if (p == NP - 1 && t == 0) offsets[N_NODES] = sc[NP - 1];
    __syncthreads();

    const unsigned* mypk = packed + (size_t)p * PCAP;
    hist[t] = 0; cnt[t] = 0;
    __syncthreads();
    for (int i = t; i < ne; i += 256)
        atomicAdd(&hist[(mypk[i] >> 16) & 255], 1);
    __syncthreads();
    sc[t] = hist[t];
    __syncthreads();
    for (int off = 1; off < 256; off <<= 1) {
        int add = (t >= off) ? sc[t - off] : 0;
        __syncthreads();
        sc[t] += add;
        __syncthreads();
    }
    lofs[t] = sc[t] - hist[t];
    int node = p * 256 + t;
    if (node < N_NODES) offsets[node] = pb + lofs[t];
    __syncthreads();
    for (int i = t; i < ne; i += 256) {
        unsigned vv = mypk[i];
        int dl = (vv >> 16) & 255;
        int slot = lofs[dl] + atomicAdd(&cnt[dl], 1);
        lcsr[slot] = (unsigned short)(vv & 0xFFFFu);
    }
    __syncthreads();
    for (int i = t; i < ne; i += 256) csr[pb + i] = lcsr[i];
}

// ---------------- Fused layer: gather (16 waves) + MFMA (4 waves) ---------
// Block = 1024 thr = 16 waves = 16 nodes (one MFMA M-tile). Each wave runs
// the r9-proven gather body for its node -> LDS aggT. Waves 0-3 then each
// compute one 16x16 col-tile (4 MFMAs, own weight frags); 128 threads store
// 16 rows coalesced. Kills the agg global round-trip + 3 linear dispatches.

template <int RELU>
__global__ __launch_bounds__(1024) void layer_kernel(
    const unsigned short* __restrict__ hin,
    const int* __restrict__ offsets, const unsigned short* __restrict__ csr_src,
    const float* __restrict__ Wrel, const float* __restrict__ bias,
    const float* __restrict__ Wroot, unsigned short* __restrict__ hout) {
    __shared__ unsigned short aggT[16][72];   // stride 72: bank-spread
    __shared__ unsigned short outT[16][72];

    const int tid = threadIdx.x;
    const int w = tid >> 6, lane = tid & 63;
    const int half = lane >> 5, hl = lane & 31;
    const int g0 = blockIdx.x * 16;           // 3125 * 16 = 50000 exactly
    const int n = g0 + w;

    // ---- gather phase: one wave per node, 32-edge buffered rounds ----
    const int beg = offsets[n], end = offsets[n + 1];
    float accx = 0.f, accy = 0.f;
    for (int base = beg; base < end; base += 64) {
        int cnt = min(64, end - base);
        int sidx = (base + lane < end) ? (int)csr_src[base + lane] : 0;
        for (int kb = 0; kb < cnt; kb += 32) {
            unsigned u[16];
#pragma unroll
            for (int p = 0; p < 16; ++p) {     // 16 independent dual-row loads
                int e = kb + 2 * p + half;
                int r = __shfl(sidx, e);
                u[p] = (e < cnt) ? *((const unsigned*)(hin + (size_t)r * 64) + hl) : 0u;
            }
#pragma unroll
            for (int p = 0; p < 16; ++p) {
                accx += __uint_as_float(u[p] << 16);
                accy += __uint_as_float(u[p] & 0xffff0000u);
            }
        }
    }
    float ox = accx + __shfl(accx, lane ^ 32);
    float oy = accy + __shfl(accy, lane ^ 32);
    if (half == 0)
        *((unsigned*)&aggT[w][0] + hl) = pack_bf16x2(ox, oy);
    __syncthreads();   // agg tile complete

    // ---- linear phase: wave t (t<4) computes col-tile t ----
    if (w < 4) {
        const int q = lane >> 4, c = lane & 15;
        const int o = w * 16 + c;
        const float biasv = bias[o];
        short8 brel_[2], broot_[2];
#pragma unroll
        for (int s = 0; s < 2; ++s) {
            const float4* pr = (const float4*)(Wrel  + o * 64 + s * 32 + q * 8);
            const float4* po = (const float4*)(Wroot + o * 64 + s * 32 + q * 8);
            float4 r0 = pr[0], r1 = pr[1], z0 = po[0], z1 = po[1];
            short8 rr, zz;
            rr[0] = (short)bf16rne(r0.x); rr[1] = (short)bf16rne(r0.y);
            rr[2] = (short)bf16rne(r0.z); rr[3] = (short)bf16rne(r0.w);
            rr[4] = (short)bf16rne(r1.x); rr[5] = (short)bf16rne(r1.y);
            rr[6] = (short)bf16rne(r1.z); rr[7] = (short)bf16rne(r1.w);
            zz[0] = (short)bf16rne(z0.x); zz[1] = (short)bf16rne(z0.y);
            zz[2] = (short)bf16rne(z0.z); zz[3] = (short)bf16rne(z0.w);
            zz[4] = (short)bf16rne(z1.x); zz[5] = (short)bf16rne(z1.y);
            zz[6] = (short)bf16rne(z1.z); zz[7] = (short)bf16rne(z1.w);
            brel_[s] = rr; broot_[s] = zz;
        }
        short8 a_agg[2], a_x[2];
#pragma unroll
        for (int s = 0; s < 2; ++s) {
            a_agg[s] = *(const short8*)&aggT[c][s * 32 + q * 8];
            a_x[s]   = *(const short8*)(hin + (size_t)(g0 + c) * 64 + s * 32 + q * 8);
        }
        f32x4 a0 = {biasv, biasv, biasv, biasv};
        a0 = __builtin_amdgcn_mfma_f32_16x16x32_bf16(a_agg[0], brel_[0], a0, 0, 0, 0);
        a0 = __builtin_amdgcn_mfma_f32_16x16x32_bf16(a_agg[1], brel_[1], a0, 0, 0, 0);
        a0 = __builtin_amdgcn_mfma_f32_16x16x32_bf16(a_x[0],  broot_[0], a0, 0, 0, 0);
        a0 = __builtin_amdgcn_mfma_f32_16x16x32_bf16(a_x[1],  broot_[1], a0, 0, 0, 0);
        // C/D layout: col=lane&15, row=q*4+reg
#pragma unroll
        for (int r = 0; r < 4; ++r) {
            float v = a0[r];
            if (RELU) v = fmaxf(v, 0.f);
            outT[q * 4 + r][w * 16 + c] = (unsigned short)bf16rne(v);
        }
    }
    __syncthreads();   // all 16 waves execute both barriers (safe semantics)

    // ---- store: 128 threads, 16 rows x 8 lanes x 16 B coalesced ----
    if (tid < 128) {
        int row = tid >> 3;
        int ch = (tid & 7) * 8;
        short8 v = *(const short8*)&outT[row][ch];
        *(short8*)(hout + (size_t)(g0 + row) * 64 + ch) = v;
    }
}

// ---------------- Pool + classifier: one block per graph ------------------
// batch is sorted: graph g's nodes are a contiguous range, found by binary
// search. No atomics, no zero-init.

__global__ __launch_bounds__(256) void poolfinal_kernel(
    const unsigned short* __restrict__ h, const int* __restrict__ batch,
    const float* __restrict__ Wlin, const float* __restrict__ blin,
    float* __restrict__ out) {
    __shared__ float part[4][64];
    const int g = blockIdx.x;
    const int tid = threadIdx.x, w = tid >> 6, lane = tid & 63;

    int a = 0, b = N_NODES;                    // lo: first idx with batch >= g
    while (a < b) { int m = (a + b) >> 1; if (batch[m] < g) a = m + 1; else b = m; }
    const int lo = a;
    b = N_NODES;                               // hi: first idx with batch >= g+1
    while (a < b) { int m = (a + b) >> 1; if (batch[m] < g + 1) a = m + 1; else b = m; }
    const int hi = a;

    float acc = 0.f;
    for (int n = lo + w; n < hi; n += 4) {
        unsigned u = h[(size_t)n * 64 + lane];
        acc += __uint_as_float(u << 16);
    }
    part[w][lane] = acc;
    __syncthreads();
    if (w == 0) {
        float s = part[0][lane] + part[1][lane] + part[2][lane] + part[3][lane];
        float cdiv = fmaxf((float)(hi - lo), 1.0f);
        float pv = s / cdiv;
        out[g * 64 + lane] = pv;               // pooled output
        part[0][lane] = pv;
    }
    __syncthreads();
    if (tid < N_CLASSES) {
        float o = blin[tid];
#pragma unroll
        for (int k = 0; k < 64; ++k) o += part[0][k] * Wlin[tid * 64 + k];
        out[N_GRAPHS * 64 + g * N_CLASSES + tid] = o;   // classifier output
    }
}

// ---------------- Launch (7 dispatches) ----------------

extern "C" void kernel_launch(void* const* d_in, const int* in_sizes, int n_in,
                              void* d_out, int out_size, void* d_ws, size_t ws_size,
                              hipStream_t stream) {
    const float* x     = (const float*)d_in[0];
    const int*   ei    = (const int*)d_in[1];
    const int*   batch = (const int*)d_in[2];
    const float* W1r = (const float*)d_in[3];
    const float* b1  = (const float*)d_in[4];
    const float* W1o = (const float*)d_in[5];
    const float* W2r = (const float*)d_in[6];
    const float* b2  = (const float*)d_in[7];
    const float* W2o = (const float*)d_in[8];
    const float* W3r = (const float*)d_in[9];
    const float* b3  = (const float*)d_in[10];
    const float* W3o = (const float*)d_in[11];
    const float* Wl  = (const float*)d_in[12];
    const float* bl  = (const float*)d_in[13];
    float* out = (float*)d_out;

    const int E = in_sizes[1] / 2;
    const int* src = ei;
    const int* dst = ei + E;

    char* p = (char*)d_ws;
    unsigned short* xb  = (unsigned short*)p; p += (size_t)N_NODES * 64 * 2;
    unsigned short* h1  = (unsigned short*)p; p += (size_t)N_NODES * 64 * 2;
    unsigned short* h2  = (unsigned short*)p; p += (size_t)N_NODES * 64 * 2;
    unsigned short* h3  = h1;                  // layer-3 output reuses h1
    unsigned* packed    = (unsigned*)p; p += (size_t)NP * PCAP * 4;
    unsigned short* csr = (unsigned short*)p; p += (size_t)E * 2;
    int* offsets   = (int*)p;   p += (size_t)(N_NODES + 1) * 4;
    int* gcursor   = (int*)p;   p += NP * 4;

    const int NCHUNK = (E + EPA - 1) / EPA;  // 153
    cvt_kernel<<<(N_NODES * 16 + 255) / 256, 256, 0, stream>>>(x, xb, gcursor);
    bucket_kernel<<<NCHUNK, 256, 0, stream>>>(src, dst, gcursor, packed, E);
    build_kernel<<<NP, 256, 0, stream>>>(packed, gcursor, offsets, csr);

    const int LB = N_NODES / 16;           // 3125 blocks, 16 nodes each
    layer_kernel<1><<<LB, 1024, 0, stream>>>(xb, offsets, csr, W1r, b1, W1o, h1);
    layer_kernel<1><<<LB, 1024, 0, stream>>>(h1, offsets, csr, W2r, b2, W2o, h2);
    layer_kernel<0><<<LB, 1024, 0, stream>>>(h2, offsets, csr, W3r, b3, W3o, h3);

    poolfinal_kernel<<<N_GRAPHS, 256, 0, stream>>>(h3, batch, Wl, bl, out);
}